// Round 2
// baseline (308.924 us; speedup 1.0000x reference)
//
#include <hip/hip_runtime.h>
#include <stdint.h>

#define BATCH 8
#define NC 80
#define NA1 8112
#define NA2 2028
#define NA3 507
#define NTOT 10647
#define NPAD 10656           /* NTOT padded to x4 and 64B-aligned rows */
#define NTILES 84            /* ceil(NTOT/128) */
#define KSEL 256
#define MAXPC 100
#define MAXTOT 100
#define NEGV -1000000000.0f
#define SCTHR 0.3f
#define IOUTHR 0.5f
#define M2 (NC * KSEL)       /* 20480 per image */
#define MAXCAND 8000         /* <=100 kept per class * 80 classes */

typedef unsigned long long ull;

// static device scratch, fully rewritten every launch
__device__ unsigned g_keys[BATCH * NC * NPAD];   // transposed score keys, 27.3 MB
__device__ float g_s[BATCH * NC * KSEL];
__device__ int   g_n[BATCH * NC * KSEL];

__device__ __forceinline__ unsigned okey(float f) {
  unsigned u = __float_as_uint(f);
  return u ^ ((unsigned)((int)u >> 31) | 0x80000000u);
}
__device__ __forceinline__ float inv_okey(unsigned k) {
  unsigned u = (k & 0x80000000u) ? (k ^ 0x80000000u) : ~k;
  return __uint_as_float(u);
}

// top-kwant threshold via 4x8-bit radix; per-wave sub-histograms (hist4[1024])
__device__ void radix_select256(const unsigned* keys, int cnt, unsigned kwant,
                                unsigned* hist4, unsigned* suf, unsigned* s_sel,
                                unsigned& T_out, unsigned& need_out)
{
  const int tid = threadIdx.x;
  const int wb = (tid >> 6) << 8;
  unsigned need = kwant, prefix = 0;
  for (int shift = 24; shift >= 0; shift -= 8) {
    hist4[tid] = 0; hist4[tid + 256] = 0; hist4[tid + 512] = 0; hist4[tid + 768] = 0;
    __syncthreads();
    unsigned maskhi = (shift == 24) ? 0u : (0xFFFFFFFFu << (shift + 8));
    for (int n = tid; n < cnt; n += 256) {
      unsigned k = keys[n];
      if ((k & maskhi) == prefix) atomicAdd(&hist4[wb + ((k >> shift) & 255u)], 1u);
    }
    __syncthreads();
    suf[tid] = hist4[tid] + hist4[tid + 256] + hist4[tid + 512] + hist4[tid + 768];
    __syncthreads();
    for (int off = 1; off < 256; off <<= 1) {   // inclusive suffix sum
      unsigned v = suf[tid] + ((tid + off < 256) ? suf[tid + off] : 0u);
      __syncthreads();
      suf[tid] = v;
      __syncthreads();
    }
    unsigned mys = suf[tid];
    unsigned nxt = (tid == 255) ? 0u : suf[tid + 1];
    if (mys >= need && nxt < need) {
      s_sel[0] = prefix | ((unsigned)tid << shift);
      s_sel[1] = need - nxt;
    }
    __syncthreads();
    prefix = s_sel[0];
    need = s_sel[1];
    __syncthreads();
  }
  T_out = prefix;
  need_out = need;
}

// Kernel A: compute scores coalesced, transpose to [b][c][n] key layout
__global__ __launch_bounds__(256)
void score_transpose(const float* __restrict__ c1, const float* __restrict__ p1,
                     const float* __restrict__ c2, const float* __restrict__ p2,
                     const float* __restrict__ c3, const float* __restrict__ p3)
{
  const int tid = threadIdx.x;
  const int b = blockIdx.x / NTILES;
  const int tile = blockIdx.x % NTILES;
  const int n0 = tile * 128;

  __shared__ unsigned skey[128 * 81];   // padded rows: conflict-free transpose
  __shared__ float sconf[128];

  if (tid < 128) {
    int ng = n0 + tid;
    float cf = 0.0f;
    if (ng < NTOT) {
      if (ng < NA1)            cf = c1[b * NA1 + ng];
      else if (ng < NA1 + NA2) cf = c2[b * NA2 + ng - NA1];
      else                     cf = c3[b * NA3 + ng - NA1 - NA2];
    }
    sconf[tid] = cf;
  }
  __syncthreads();

  // 128 anchors x 80 classes = 2560 float4 elements, each float4 within one anchor
  for (int e4 = tid; e4 < 2560; e4 += 256) {
    int a = e4 / 20;
    int ng = n0 + a;
    if (ng >= NTOT) continue;
    int cls0 = (e4 % 20) * 4;
    const float* pp; int nl;
    if (ng < NA1)            { pp = p1 + (size_t)b * NA1 * NC; nl = ng; }
    else if (ng < NA1 + NA2) { pp = p2 + (size_t)b * NA2 * NC; nl = ng - NA1; }
    else                     { pp = p3 + (size_t)b * NA3 * NC; nl = ng - NA1 - NA2; }
    float4 pv = *(const float4*)(pp + (size_t)nl * NC + cls0);
    float cf = sconf[a];
    skey[a * 81 + cls0 + 0] = okey(pv.x * cf);
    skey[a * 81 + cls0 + 1] = okey(pv.y * cf);
    skey[a * 81 + cls0 + 2] = okey(pv.z * cf);
    skey[a * 81 + cls0 + 3] = okey(pv.w * cf);
  }
  __syncthreads();

  // write transposed: per class, 128 contiguous keys
  for (int o = tid; o < 80 * 128; o += 256) {
    int cc = o >> 7, nn = o & 127;
    int idx = n0 + nn;
    if (idx < NTOT)
      g_keys[((size_t)(b * NC + cc)) * NPAD + idx] = skey[nn * 81 + cc];
    else if (idx < NPAD)
      g_keys[((size_t)(b * NC + cc)) * NPAD + idx] = 0u;   // pad sinks to bottom
  }
}

// Kernel B: per (b,c) top-256 select + sort + NMS via suppression bitmasks
__global__ __launch_bounds__(256)
void nms_per_class(const float* __restrict__ b1, const float* __restrict__ b2,
                   const float* __restrict__ b3)
{
  const int tid = threadIdx.x;
  const int b = blockIdx.x / NC;

  __shared__ alignas(16) unsigned sarr[NPAD];     // reused later as supp masks
  __shared__ alignas(8) unsigned hist4[1024];     // reused later as cand
  __shared__ unsigned suf[256];
  __shared__ unsigned s_sel[2];
  __shared__ int s_cgt, s_ceq;
  __shared__ float4 cbox[KSEL];
  __shared__ float csc[KSEL];
  __shared__ unsigned char keptf[KSEL];
  ull* cand = (ull*)hist4;
  ull* supp = (ull*)sarr;

  // stage this class's key row (coalesced uint4)
  {
    const uint4* r4 = (const uint4*)(g_keys + (size_t)blockIdx.x * NPAD);
    uint4* s4 = (uint4*)sarr;
    for (int i = tid; i < NPAD / 4; i += 256) s4[i] = r4[i];
  }
  __syncthreads();

  unsigned T, need;
  radix_select256(sarr, NTOT, KSEL, hist4, suf, s_sel, T, need);

  if (tid == 0) { s_cgt = 0; s_ceq = 0; }
  __syncthreads();
  const int ngt = KSEL - (int)need;
  for (int n = tid; n < NTOT; n += 256) {
    unsigned k = sarr[n];
    if (k > T) {
      int p = atomicAdd(&s_cgt, 1);
      cand[p] = ((ull)k << 32) | (unsigned)(~n);
    } else if (k == T) {
      int p = atomicAdd(&s_ceq, 1);
      if (p < (int)need) cand[ngt + p] = ((ull)k << 32) | (unsigned)(~n);
    }
  }
  __syncthreads();

  // bitonic sort 256 descending by (key, ~n)
  for (int kk = 2; kk <= KSEL; kk <<= 1) {
    for (int j = kk >> 1; j > 0; j >>= 1) {
      int ixj = tid ^ j;
      if (ixj > tid) {
        ull a = cand[tid], cc = cand[ixj];
        if (((tid & kk) == 0) ? (a < cc) : (a > cc)) { cand[tid] = cc; cand[ixj] = a; }
      }
      __syncthreads();
    }
  }

  int myn;
  {
    ull ck = cand[tid];
    myn = (int)(~(unsigned)ck);
    csc[tid] = inv_okey((unsigned)(ck >> 32));
    const float* bp;
    if (myn < NA1)            bp = b1 + (size_t)(b * NA1 + myn) * 4;
    else if (myn < NA1 + NA2) bp = b2 + (size_t)(b * NA2 + (myn - NA1)) * 4;
    else                      bp = b3 + (size_t)(b * NA3 + (myn - NA1 - NA2)) * 4;
    cbox[tid] = make_float4(bp[0], bp[1], bp[2], bp[3]);
  }
  __syncthreads();

  // each thread i builds its suppression row: bits j>i with iou(i,j)>thr
  {
    const float4 mb = cbox[tid];
    const float myarea = (mb.z - mb.x) * (mb.w - mb.y);
    ull m0 = 0, m1 = 0, m2 = 0, m3 = 0;
    for (int j = 0; j < KSEL; ++j) {
      float4 bj = cbox[j];            // LDS broadcast
      float ja = (bj.z - bj.x) * (bj.w - bj.y);
      float iy = fmaxf(fminf(bj.z, mb.z) - fmaxf(bj.x, mb.x), 0.0f);
      float ix = fmaxf(fminf(bj.w, mb.w) - fmaxf(bj.y, mb.y), 0.0f);
      float inter = iy * ix;
      float uni = ja + myarea - inter;
      bool sup = (j > tid) && (uni > 0.0f) && (inter > IOUTHR * uni);
      ull bit = sup ? (1ull << (j & 63)) : 0ull;
      if ((j >> 6) == 0) m0 |= bit; else if ((j >> 6) == 1) m1 |= bit;
      else if ((j >> 6) == 2) m2 |= bit; else m3 |= bit;
    }
    supp[tid * 4 + 0] = m0; supp[tid * 4 + 1] = m1;
    supp[tid * 4 + 2] = m2; supp[tid * 4 + 3] = m3;
  }
  __syncthreads();

  if (tid == 0) {   // sequential greedy scan over bitmasks
    ull keep0 = ~0ull, keep1 = ~0ull, keep2 = ~0ull, keep3 = ~0ull;
    int run = 0;
    for (int i = 0; i < KSEL; ++i) {
      ull kw = (i < 64) ? keep0 : (i < 128) ? keep1 : (i < 192) ? keep2 : keep3;
      bool cur = ((kw >> (i & 63)) & 1ull) && (csc[i] > SCTHR);
      unsigned char kf = 0;
      if (cur) {
        keep0 &= ~supp[i * 4 + 0]; keep1 &= ~supp[i * 4 + 1];
        keep2 &= ~supp[i * 4 + 2]; keep3 &= ~supp[i * 4 + 3];
        if (++run <= MAXPC) kf = 1;
      }
      keptf[i] = kf;
    }
  }
  __syncthreads();

  const size_t base = (size_t)blockIdx.x * KSEL + tid;
  g_s[base] = keptf[tid] ? csc[tid] : NEGV;
  g_n[base] = myn;
}

// Kernel C: per-image top-100 merge + output
__global__ __launch_bounds__(256)
void nms_final(const float* __restrict__ b1, const float* __restrict__ b2,
               const float* __restrict__ b3, float* __restrict__ out)
{
  const int tid = threadIdx.x;
  const int b = blockIdx.x;

  __shared__ unsigned lk[MAXCAND];
  __shared__ unsigned short lfi[MAXCAND];
  __shared__ unsigned hist4[1024];
  __shared__ unsigned suf[256];
  __shared__ unsigned s_sel[2];
  __shared__ int s_cnt, s_cgt, s_ceq, s_nv;
  __shared__ ull cand[128];

  if (tid == 0) s_cnt = 0;
  __syncthreads();

  const float* s = g_s + (size_t)b * M2;
  for (int base2 = 0; base2 < M2; base2 += 256) {
    int fi = base2 + tid;
    float sc = s[fi];
    bool pred = sc > SCTHR;
    ull mask = __ballot(pred);
    if (mask != 0ULL) {
      int lane = tid & 63;
      int ldr = __ffsll(mask) - 1;
      int wb = 0;
      if (lane == ldr) wb = atomicAdd(&s_cnt, __popcll(mask));
      wb = __shfl(wb, ldr, 64);
      if (pred) {
        int pos = wb + __popcll(mask & ((1ULL << lane) - 1ULL));
        lk[pos] = okey(sc);
        lfi[pos] = (unsigned short)fi;
      }
    }
  }
  __syncthreads();
  const int cnt = s_cnt;

  if (tid < 128) cand[tid] = 0ULL;
  __syncthreads();

  if (cnt <= MAXTOT) {
    if (tid < cnt)
      cand[tid] = ((ull)lk[tid] << 16) | (unsigned)((~lfi[tid]) & 0xFFFF);
    __syncthreads();
  } else {
    unsigned T, need;
    radix_select256(lk, cnt, MAXTOT, hist4, suf, s_sel, T, need);
    if (tid == 0) { s_cgt = 0; s_ceq = 0; }
    __syncthreads();
    const int ngt = MAXTOT - (int)need;
    for (int i = tid; i < cnt; i += 256) {
      unsigned k = lk[i];
      if (k > T) {
        int p = atomicAdd(&s_cgt, 1);
        cand[p] = ((ull)k << 16) | (unsigned)((~lfi[i]) & 0xFFFF);
      } else if (k == T) {
        int p = atomicAdd(&s_ceq, 1);
        if (p < (int)need) cand[ngt + p] = ((ull)k << 16) | (unsigned)((~lfi[i]) & 0xFFFF);
      }
    }
    __syncthreads();
  }

  for (int kk = 2; kk <= 128; kk <<= 1) {
    for (int j = kk >> 1; j > 0; j >>= 1) {
      if (tid < 128) {
        int ixj = tid ^ j;
        if (ixj > tid) {
          ull a = cand[tid], cc = cand[ixj];
          if (((tid & kk) == 0) ? (a < cc) : (a > cc)) { cand[tid] = cc; cand[ixj] = a; }
        }
      }
      __syncthreads();
    }
  }

  if (tid == 0) s_nv = 0;
  __syncthreads();

  if (tid < MAXTOT) {
    ull ck = cand[tid];
    float o0 = 0.f, o1 = 0.f, o2 = 0.f, o3 = 0.f, osc = 0.f, ocl = 0.f;
    if (ck != 0ULL) {
      unsigned k = (unsigned)(ck >> 16);
      int fi = (int)((~(unsigned)ck) & 0xFFFFu);
      float sc = inv_okey(k);
      if (sc > SCTHR) {
        int cls = fi >> 8;
        int n = g_n[(size_t)b * M2 + fi];
        const float* bp;
        if (n < NA1)            bp = b1 + (size_t)(b * NA1 + n) * 4;
        else if (n < NA1 + NA2) bp = b2 + (size_t)(b * NA2 + (n - NA1)) * 4;
        else                    bp = b3 + (size_t)(b * NA3 + (n - NA1 - NA2)) * 4;
        o0 = fminf(fmaxf(bp[0], 0.0f), 1.0f);
        o1 = fminf(fmaxf(bp[1], 0.0f), 1.0f);
        o2 = fminf(fmaxf(bp[2], 0.0f), 1.0f);
        o3 = fminf(fmaxf(bp[3], 0.0f), 1.0f);
        osc = sc;
        ocl = (float)cls;
        atomicAdd(&s_nv, 1);
      }
    }
    int oi = b * MAXTOT + tid;
    out[(size_t)oi * 4 + 0] = o0;
    out[(size_t)oi * 4 + 1] = o1;
    out[(size_t)oi * 4 + 2] = o2;
    out[(size_t)oi * 4 + 3] = o3;
    out[BATCH * MAXTOT * 4 + oi] = osc;
    out[BATCH * MAXTOT * 5 + oi] = ocl;
  }
  __syncthreads();
  if (tid == 0) out[BATCH * MAXTOT * 6 + b] = (float)s_nv;
}

extern "C" void kernel_launch(void* const* d_in, const int* in_sizes, int n_in,
                              void* d_out, int out_size, void* d_ws, size_t ws_size,
                              hipStream_t stream) {
  const float* b1 = (const float*)d_in[0];
  const float* c1 = (const float*)d_in[1];
  const float* p1 = (const float*)d_in[2];
  const float* b2 = (const float*)d_in[3];
  const float* c2 = (const float*)d_in[4];
  const float* p2 = (const float*)d_in[5];
  const float* b3 = (const float*)d_in[6];
  const float* c3 = (const float*)d_in[7];
  const float* p3 = (const float*)d_in[8];
  (void)in_sizes; (void)n_in; (void)out_size; (void)d_ws; (void)ws_size;

  score_transpose<<<dim3(BATCH * NTILES), dim3(256), 0, stream>>>(c1, p1, c2, p2, c3, p3);
  nms_per_class<<<dim3(BATCH * NC), dim3(256), 0, stream>>>(b1, b2, b3);
  nms_final<<<dim3(BATCH), dim3(256), 0, stream>>>(b1, b2, b3, (float*)d_out);
}